// Round 8
// baseline (7852.145 us; speedup 1.0000x reference)
//
#include <hip/hip_runtime.h>
#include <stdint.h>

// Must match numpy float32 rounding exactly: (dx*dx + dy*dy) + dz*dz, no FMA.
#pragma clang fp contract(off)

#define NPT      2048
#define NBATCH   32
#define NPTS     65536
#define MEMBERS  8
#define NTHREADS 512
#define CHUNK    (NPTS / MEMBERS)       // 8192 points per block
#define PPT      (CHUNK / NTHREADS)     // 16 points per thread
#define WPB      (NTHREADS / 64)        // 8 waves per block
#define LINEPAD  16                     // 128B per (batch,parity) slot line

__device__ __forceinline__ uint32_t f2u(float f) { return __float_as_uint(f); }
__device__ __forceinline__ float u2f(uint32_t u) { return __uint_as_float(u); }

// argmax combine: larger value wins; tie -> smaller index (numpy argmax order)
__device__ __forceinline__ void amerge(float& v, int& i, float ov, int oi) {
    if (ov > v || (ov == v && oi < i)) { v = ov; i = oi; }
}
template<int CTRL>
__device__ __forceinline__ void dpp_round(float& v, int& i) {
    float ov = u2f((uint32_t)__builtin_amdgcn_mov_dpp((int)f2u(v), CTRL, 0xf, 0xf, true));
    int   oi = __builtin_amdgcn_mov_dpp(i, CTRL, 0xf, 0xf, true);
    amerge(v, i, ov, oi);
}
__device__ __forceinline__ void swz16_round(float& v, int& i) {   // lane ^ 16
    float ov = u2f((uint32_t)__builtin_amdgcn_ds_swizzle((int)f2u(v), 0x401F));
    int   oi = __builtin_amdgcn_ds_swizzle(i, 0x401F);
    amerge(v, i, ov, oi);
}
// reduce within each row of 16 lanes
__device__ __forceinline__ void row16_argmax(float& v, int& i) {
    dpp_round<0xB1>(v, i);    // quad_perm xor1
    dpp_round<0x4E>(v, i);    // quad_perm xor2
    dpp_round<0x141>(v, i);   // row_half_mirror (merge 4-groups)
    dpp_round<0x140>(v, i);   // row_mirror      (merge 8-groups)
}
// reduce over 8 candidates held at slot (lane&7)
__device__ __forceinline__ void oct_argmax(float& v, int& i) {
    dpp_round<0xB1>(v, i);
    dpp_round<0x4E>(v, i);
    dpp_round<0x141>(v, i);
}

// Fast-path (same-XCD) slot access: plain store is write-through to the XCD's
// L2; sc0 load bypasses only L1 and reads that L2. Visibility across XCDs is
// NOT guaranteed -> a correct agent-scope fallback path always exists below.
__device__ __forceinline__ uint64_t load_sc0_b64(const uint64_t* p) {
    uint64_t w;
    asm volatile("global_load_dwordx2 %0, %1, off sc0\n\t"
                 "s_waitcnt vmcnt(0)"
                 : "=v"(w) : "v"(p) : "memory");
    return w;
}
__device__ __forceinline__ void store_plain_b64(uint64_t* p, uint64_t w) {
    asm volatile("global_store_dwordx2 %0, %1, off"
                 :: "v"(p), "v"(w) : "memory");
}

__global__ void __launch_bounds__(NTHREADS)
fps_kernel(const float* __restrict__ xyz, int* __restrict__ out,
           uint64_t* __restrict__ ws)
{
    // ws: fast[32][2][LINEPAD] then safe[32][2][LINEPAD] (u64 granurality)
    uint64_t* fastq = ws;
    uint64_t* safeq = ws + NBATCH * 2 * LINEPAD;

    // x in LDS purely as register relief: each thread touches only its own
    // 16 slots (p = tid + k*512) -> no barriers, conflict-free.
    __shared__ float    sx[CHUNK];   // 32 KB
    __shared__ uint64_t red[WPB * 4];
    __shared__ uint32_t bc[4];

    // Swizzle: a batch's 8 members share blockIdx%8 -> same XCD under the
    // round-robin dispatch heuristic (fast path); correctness never depends
    // on it (agent-scope fallback).
    const int i = blockIdx.x;
    const int q = i >> 3;
    const int batch  = (i & 7) * 4 + (q & 3);   // [0,32)
    const int member = q >> 2;                  // [0,8)
    const int tid  = threadIdx.x;
    const int lane = tid & 63;
    const int wv   = tid >> 6;

    const float* xb = xyz + (size_t)batch * 3 * NPTS;
    const int gbase = member * CHUNK;

    float py[PPT], pz[PPT], pd[PPT];    // 48 data floats (R6: 48 VGPR, no spill)
#pragma unroll
    for (int k = 0; k < PPT; ++k) {
        int p = tid + k * NTHREADS;
        int g = gbase + p;
        sx[p] = xb[g];
        py[k] = xb[NPTS + g];
        pz[k] = xb[2 * NPTS + g];
        pd[k] = 1e10f;
    }

    // First centroid is point 0; first emitted index is 0.
    float cx = xb[0], cy = xb[NPTS], cz = xb[2 * NPTS];
    if (member == 0 && tid == 0) out[(size_t)batch * NPT] = 0;

    uint64_t* fb = fastq + (size_t)batch * 2 * LINEPAD;
    uint64_t* qb = safeq + (size_t)batch * 2 * LINEPAD;

    for (int t = 0; t < NPT - 1; ++t) {
        // ---- dist update + per-thread argmax. Track 4-bit k (inline-const
        //      cndmask) + v_max for the value: strict >, ascending k ->
        //      first-occurrence semantics identical to numpy argmax. ----
        float bv = -1.0f;            // all dists >= 0, so always beaten
        int   bk = 0;
#pragma unroll
        for (int k = 0; k < PPT; ++k) {
            int p = tid + k * NTHREADS;
            float dx = sx[p] - cx;
            float dy = py[k] - cy;
            float dz = pz[k] - cz;
            float d  = dx * dx + dy * dy;   // contract(off): mul,mul,add
            d = d + dz * dz;                // then add — matches numpy order
            float nd = fminf(pd[k], d);
            pd[k] = nd;
            bool g = nd > bv;
            bv = fmaxf(bv, nd);
            bk = g ? k : bk;
        }
        int bi = gbase + tid + (bk << 9);   // reconstruct global index once

        // ---- row-of-16 argmax (4 DPP rounds), one writer per row ----
        row16_argmax(bv, bi);
        if ((lane & 15) == 0)
            red[wv * 4 + (lane >> 4)] = ((uint64_t)f2u(bv) << 32) | (uint32_t)bi;
        __syncthreads();

        if (wv == 0) {
            __builtin_amdgcn_s_setprio(1);
            // ---- cross-wave reduce over the 32 candidates ----
            uint64_t c = red[lane & 31];
            float v  = u2f((uint32_t)(c >> 32));
            int   ix = (int)(uint32_t)(c & 0xFFFFFFFFu);
            row16_argmax(v, ix);
            swz16_round(v, ix);      // block best everywhere

            // ---- publish block-best: fast (same-XCD L2) + safe (agent/L3).
            // Tag-in-word self-validates; ABA-safe (parity + monotone tags,
            // t+2 rewrite gated on all blocks passing poll t+1); 0xAAAA
            // poison / prior-replay tags (2046/2045) never match first polls
            // (0/1) -> no memset needed. ----
            uint64_t* sfb = fb + (size_t)(t & 1) * LINEPAD;
            uint64_t* sqb = qb + (size_t)(t & 1) * LINEPAD;
            const uint32_t tag = (uint32_t)t;
            if (lane == 0) {
                uint64_t w = ((uint64_t)f2u(v) << 32)
                           | ((uint64_t)(uint32_t)ix << 16) | tag;
                store_plain_b64(&sfb[member], w);                    // fast
                __hip_atomic_store(&sqb[member], w, __ATOMIC_RELAXED,
                                   __HIP_MEMORY_SCOPE_AGENT);        // safe
            }

            // ---- poll: lane l watches slot l&7. Fast line first; after 16
            //      spins also check the agent-scope line (any-placement safe).
            uint64_t w = 0; bool done = false; int spins = 0;
            do {
                if (!done) {
                    uint64_t wf = load_sc0_b64(&sfb[lane & 7]);
                    if ((uint32_t)(wf & 0xFFFFu) == tag) { w = wf; done = true; }
                }
                if (!done && spins >= 16) {
                    uint64_t wsf = __hip_atomic_load(&sqb[lane & 7],
                                                     __ATOMIC_RELAXED,
                                                     __HIP_MEMORY_SCOPE_AGENT);
                    if ((uint32_t)(wsf & 0xFFFFu) == tag) { w = wsf; done = true; }
                }
                ++spins;
            } while (!__all(done));

            // ---- global argmax across the 8 member candidates ----
            float gv = u2f((uint32_t)(w >> 32));
            int   gi = (int)((w >> 16) & 0xFFFFu);
            oct_argmax(gv, gi);

            // winner coords (read-only global, L2-cached) + output index
            if (lane < 3) bc[lane] = f2u(xb[(size_t)lane * NPTS + gi]);
            if (lane == 0 && member == 0) out[(size_t)batch * NPT + t + 1] = gi;
            __builtin_amdgcn_s_setprio(0);
        }
        __syncthreads();
        cx = u2f(bc[0]); cy = u2f(bc[1]); cz = u2f(bc[2]);
    }
}

extern "C" void kernel_launch(void* const* d_in, const int* in_sizes, int n_in,
                              void* d_out, int out_size, void* d_ws, size_t ws_size,
                              hipStream_t stream)
{
    const float* xyz = (const float*)d_in[0];
    int* out = (int*)d_out;
    uint64_t* ws = (uint64_t*)d_ws;   // 2 regions x 8KB; no memset needed
    fps_kernel<<<NBATCH * MEMBERS, NTHREADS, 0, stream>>>(xyz, out, ws);
}

// Round 9
// 4572.470 us; speedup vs baseline: 1.7173x; 1.7173x over previous
//
#include <hip/hip_runtime.h>
#include <stdint.h>

// Must match numpy float32 rounding exactly: (dx*dx + dy*dy) + dz*dz, no FMA.
#pragma clang fp contract(off)

#define NPT      2048
#define NBATCH   32
#define NPTS     65536
#define MEMBERS  8
#define NTHREADS 512
#define CHUNK    (NPTS / MEMBERS)       // 8192 points per block
#define PPT      (CHUNK / NTHREADS)     // 16 points per thread
#define WPB      (NTHREADS / 64)        // 8 waves per block
#define LINEPAD  16                     // 128B per (batch,parity) slot line

__device__ __forceinline__ uint32_t f2u(float f) { return __float_as_uint(f); }
__device__ __forceinline__ float u2f(uint32_t u) { return __uint_as_float(u); }

// argmax combine: larger value wins; tie -> smaller index (numpy argmax order)
__device__ __forceinline__ void amerge(float& v, int& i, float ov, int oi) {
    if (ov > v || (ov == v && oi < i)) { v = ov; i = oi; }
}
template<int CTRL>
__device__ __forceinline__ void dpp_round(float& v, int& i) {
    float ov = u2f((uint32_t)__builtin_amdgcn_mov_dpp((int)f2u(v), CTRL, 0xf, 0xf, true));
    int   oi = __builtin_amdgcn_mov_dpp(i, CTRL, 0xf, 0xf, true);
    amerge(v, i, ov, oi);
}
__device__ __forceinline__ void swz16_round(float& v, int& i) {   // lane ^ 16
    float ov = u2f((uint32_t)__builtin_amdgcn_ds_swizzle((int)f2u(v), 0x401F));
    int   oi = __builtin_amdgcn_ds_swizzle(i, 0x401F);
    amerge(v, i, ov, oi);
}
// reduce within each row of 16 lanes
__device__ __forceinline__ void row16_argmax(float& v, int& i) {
    dpp_round<0xB1>(v, i);    // quad_perm xor1
    dpp_round<0x4E>(v, i);    // quad_perm xor2
    dpp_round<0x141>(v, i);   // row_half_mirror (merge 4-groups)
    dpp_round<0x140>(v, i);   // row_mirror      (merge 8-groups)
}
// reduce over 8 candidates held at slot (lane&7)
__device__ __forceinline__ void oct_argmax(float& v, int& i) {
    dpp_round<0xB1>(v, i);
    dpp_round<0x4E>(v, i);
    dpp_round<0x141>(v, i);
}

__global__ void __launch_bounds__(NTHREADS)
fps_kernel(const float* __restrict__ xyz, int* __restrict__ out,
           uint64_t* __restrict__ cand)
{
    // x in LDS purely as register relief: each thread touches only its own
    // 16 slots (p = tid + k*512) -> no barriers, conflict-free.
    __shared__ float    sx[CHUNK];   // 32 KB
    __shared__ uint64_t red[WPB * 4];
    __shared__ uint32_t bc[4];

    // Swizzle: a batch's 8 members share blockIdx%8 (XCD heuristic only;
    // correctness relies solely on agent-scope coherence-point ops).
    const int i = blockIdx.x;
    const int q = i >> 3;
    const int batch  = (i & 7) * 4 + (q & 3);   // [0,32)
    const int member = q >> 2;                  // [0,8)
    const int tid  = threadIdx.x;
    const int lane = tid & 63;
    const int wv   = tid >> 6;

    const float* xb = xyz + (size_t)batch * 3 * NPTS;
    const int gbase = member * CHUNK;

    float py[PPT], pz[PPT], pd[PPT];    // 48 data floats
#pragma unroll
    for (int k = 0; k < PPT; ++k) {
        int p = tid + k * NTHREADS;
        int g = gbase + p;
        sx[p] = xb[g];
        py[k] = xb[NPTS + g];
        pz[k] = xb[2 * NPTS + g];
        pd[k] = 1e10f;
    }

    // First centroid is point 0; first emitted index is 0.
    float cx = xb[0], cy = xb[NPTS], cz = xb[2 * NPTS];
    if (member == 0 && tid == 0) out[(size_t)batch * NPT] = 0;

    // cand[batch][parity][slot]: 8 live 8B slots in a padded 128B slab.
    uint64_t* cb = cand + (size_t)batch * 2 * LINEPAD;

    for (int t = 0; t < NPT - 1; ++t) {
        // ---- dist update + per-thread argmax. Track 4-bit k; strict >,
        //      ascending k -> first-occurrence semantics (numpy argmax). ----
        float bv = -1.0f;            // all dists >= 0, so always beaten
        int   bk = 0;
#pragma unroll
        for (int k = 0; k < PPT; ++k) {
            int p = tid + k * NTHREADS;
            float dx = sx[p] - cx;
            float dy = py[k] - cy;
            float dz = pz[k] - cz;
            float d  = dx * dx + dy * dy;   // contract(off): mul,mul,add
            d = d + dz * dz;                // then add — matches numpy order
            float nd = fminf(pd[k], d);
            pd[k] = nd;
            bool g = nd > bv;
            bv = fmaxf(bv, nd);
            bk = g ? k : bk;
        }
        int bi = gbase + tid + (bk << 9);   // reconstruct global index once

        // ---- row-of-16 argmax (4 DPP rounds), one writer per row ----
        row16_argmax(bv, bi);
        if ((lane & 15) == 0)
            red[wv * 4 + (lane >> 4)] = ((uint64_t)f2u(bv) << 32) | (uint32_t)bi;
        __syncthreads();

        if (wv == 0) {
            __builtin_amdgcn_s_setprio(1);
            // ---- cross-wave reduce over the 32 candidates ----
            uint64_t c = red[lane & 31];
            float v  = u2f((uint32_t)(c >> 32));
            int   ix = (int)(uint32_t)(c & 0xFFFFFFFFu);
            row16_argmax(v, ix);
            swz16_round(v, ix);      // block best everywhere

            // ---- publish block-best as one tagged relaxed 64-bit word ----
            // ABA-safe: parity + monotone tags; a slot holding t is rewritten
            // at t+2 only after all blocks passed poll t+1. Poison (0xAAAA)
            // / prior-replay tags never match current polls -> no memset.
            uint64_t* sb = cb + (size_t)(t & 1) * LINEPAD;
            const uint32_t tag = (uint32_t)t;
            if (lane == 0) {
                uint64_t w = ((uint64_t)f2u(v) << 32)
                           | ((uint64_t)(uint32_t)ix << 16) | tag;
                __hip_atomic_store(&sb[member], w, __ATOMIC_RELAXED,
                                   __HIP_MEMORY_SCOPE_AGENT);
            }

            // ---- pipelined staggered poll: 6 agent (sc1) samples of the
            //      slot line ~128c apart, checked in completion order with
            //      counted vmcnt. Retry granularity ~128c vs ~650c blocking.
            uint64_t* ap = &sb[lane & 7];
            uint64_t s0, s1, s2, s3, s4, s5;
            asm volatile(
                "s_sleep 3\n\t"
                "global_load_dwordx2 %0, %6, off sc1\n\t"
                "s_sleep 2\n\t"
                "global_load_dwordx2 %1, %6, off sc1\n\t"
                "s_sleep 2\n\t"
                "global_load_dwordx2 %2, %6, off sc1\n\t"
                "s_sleep 2\n\t"
                "global_load_dwordx2 %3, %6, off sc1\n\t"
                "s_sleep 2\n\t"
                "global_load_dwordx2 %4, %6, off sc1\n\t"
                "s_sleep 2\n\t"
                "global_load_dwordx2 %5, %6, off sc1\n\t"
                "s_waitcnt vmcnt(5)"        // s0 ready (publish store retired too)
                : "=&v"(s0), "=&v"(s1), "=&v"(s2), "=&v"(s3), "=&v"(s4), "=&v"(s5)
                : "v"(ap)
                : "memory");

            uint64_t w = s0;
            bool done = (uint32_t)(s0 & 0xFFFFu) == tag;   // per-lane latch
            if (!__all(done)) {
                asm volatile("s_waitcnt vmcnt(4)" : "+v"(s1));
                bool m = (uint32_t)(s1 & 0xFFFFu) == tag;
                if (!done && m) { w = s1; done = true; }
                if (!__all(done)) {
                    asm volatile("s_waitcnt vmcnt(3)" : "+v"(s2));
                    m = (uint32_t)(s2 & 0xFFFFu) == tag;
                    if (!done && m) { w = s2; done = true; }
                    if (!__all(done)) {
                        asm volatile("s_waitcnt vmcnt(2)" : "+v"(s3));
                        m = (uint32_t)(s3 & 0xFFFFu) == tag;
                        if (!done && m) { w = s3; done = true; }
                        if (!__all(done)) {
                            asm volatile("s_waitcnt vmcnt(1)" : "+v"(s4));
                            m = (uint32_t)(s4 & 0xFFFFu) == tag;
                            if (!done && m) { w = s4; done = true; }
                            if (!__all(done)) {
                                asm volatile("s_waitcnt vmcnt(0)" : "+v"(s5));
                                m = (uint32_t)(s5 & 0xFFFFu) == tag;
                                if (!done && m) { w = s5; done = true; }
                            }
                        }
                    }
                }
            }
            // guaranteed-progress fallback (also covers any sc1 semantics
            // surprise: stale samples can never false-match the tag)
            while (!__all(done)) {
                uint64_t x = __hip_atomic_load(ap, __ATOMIC_RELAXED,
                                               __HIP_MEMORY_SCOPE_AGENT);
                if (!done && (uint32_t)(x & 0xFFFFu) == tag) { w = x; done = true; }
            }

            // ---- global argmax across the 8 member candidates ----
            float gv = u2f((uint32_t)(w >> 32));
            int   gi = (int)((w >> 16) & 0xFFFFu);
            oct_argmax(gv, gi);

            // winner coords (read-only global, L2-cached) + output index
            if (lane < 3) bc[lane] = f2u(xb[(size_t)lane * NPTS + gi]);
            if (lane == 0 && member == 0) out[(size_t)batch * NPT + t + 1] = gi;

            // Drain ghost samples while their registers are still pinned
            // (in-flight loads write these VGPRs asynchronously; they must
            // not be reallocated until vmcnt hits 0).
            asm volatile("s_waitcnt vmcnt(0)"
                         :: "v"(s1), "v"(s2), "v"(s3), "v"(s4), "v"(s5));
            __builtin_amdgcn_s_setprio(0);
        }
        __syncthreads();
        cx = u2f(bc[0]); cy = u2f(bc[1]); cz = u2f(bc[2]);
    }
}

extern "C" void kernel_launch(void* const* d_in, const int* in_sizes, int n_in,
                              void* d_out, int out_size, void* d_ws, size_t ws_size,
                              hipStream_t stream)
{
    const float* xyz = (const float*)d_in[0];
    int* out = (int*)d_out;
    uint64_t* cand = (uint64_t*)d_ws;   // 32*2*16*8 = 8 KiB used; no memset needed
    fps_kernel<<<NBATCH * MEMBERS, NTHREADS, 0, stream>>>(xyz, out, cand);
}